// Round 4
// baseline (611.403 us; speedup 1.0000x reference)
//
#include <hip/hip_runtime.h>
#include <hip/hip_bf16.h>
#include <cstddef>
#include <cstdint>

constexpr int Bn = 8, Cn = 256, Tn = 8192;
constexpr int NL = 3;          // layers / dilations (1,2,4)
constexpr int Kc = 768;        // K for both fused GEMMs (3*256)
constexpr float SLOPE = 0.1f;

typedef unsigned short u16;
using bf8   = __attribute__((ext_vector_type(8))) short;  // 8 bf16 = 4 VGPRs
using f32x4 = __attribute__((ext_vector_type(4))) float;

__device__ __forceinline__ float lrelu(float v) { return v > 0.f ? v : SLOPE * v; }
__device__ __forceinline__ u16 f2bf(float f) {
    __hip_bfloat16 h = __float2bfloat16(f);
    return *reinterpret_cast<u16*>(&h);
}

// ---------------------------------------------------------------------------
// Weight prep (once): bf16 Wcat[l][o][s*256+c] from WC/WP/WF,
// bf16 WAp[l][o][tap*256+c] from WA[l][o][c][tap], bSum = bC+bP+bF,
// zero dummy row (ws re-poisoned each launch).
// ---------------------------------------------------------------------------
__global__ __launch_bounds__(256)
void k_wprep(const float* __restrict__ WC, const float* __restrict__ WP,
             const float* __restrict__ WF, const float* __restrict__ WA,
             const float* __restrict__ bC, const float* __restrict__ bP,
             const float* __restrict__ bF,
             u16* __restrict__ Wcat, u16* __restrict__ WAp, float* __restrict__ bSum,
             u16* __restrict__ zrow)
{
    if (blockIdx.x == 0) zrow[threadIdx.x] = 0;
    const int n1 = NL * Cn * Kc;
    for (int i = blockIdx.x * blockDim.x + threadIdx.x; i < n1;
         i += gridDim.x * blockDim.x) {
        int c = i % Cn;
        int s = (i / Cn) % 3;
        int o = (i / (3 * Cn)) % Cn;
        int l = i / (3 * Cn * Cn);
        size_t src = ((size_t)l * Cn + o) * Cn + c;
        float wc = (s == 0) ? WC[src] : (s == 1) ? WP[src] : WF[src];
        Wcat[i] = f2bf(wc);
        WAp[i] = f2bf(WA[src * 3 + s]);
    }
    for (int i = blockIdx.x * blockDim.x + threadIdx.x; i < NL * Cn;
         i += gridDim.x * blockDim.x)
        bSum[i] = bC[i] + bP[i] + bF[i];
}

// ---------------------------------------------------------------------------
// Layer-0 prep: xT[b][t][c] = bf16(lrelu(x[b][c][t]))  (transpose via LDS)
// ---------------------------------------------------------------------------
__global__ __launch_bounds__(256)
void k_prep(const float* __restrict__ x, u16* __restrict__ xT)
{
    __shared__ float s[64][65];
    const int b = blockIdx.z, c0 = blockIdx.y * 64, t0 = blockIdx.x * 64;
    const int tid = threadIdx.x;
    const float* xb = x + ((size_t)b * Cn + c0) * Tn + t0;

    int tt = tid & 63, c4 = tid >> 6;
    for (int cc = c4; cc < 64; cc += 4)
        s[cc][tt] = xb[(size_t)cc * Tn + tt];
    __syncthreads();

    int ccS = tid & 63, t4 = tid >> 6;
    u16* xTb = xT + ((size_t)b * Tn + t0) * Cn + c0;
    for (int t2 = t4; t2 < 64; t2 += 4)
        xTb[(size_t)t2 * Cn + ccS] = f2bf(lrelu(s[ccS][t2]));
}

// ---------------------------------------------------------------------------
// Fused per-layer kernel, register-direct operands (no LDS staging, no DMA):
// one block = 128 out-t x all 256 o, 512 threads (8 waves, 4-o x 2-t).
// Phase 1: Z[zr][o] = bf16(lrelu(GEMM1)), zr=0..129 (tz=t0-1+zr), Z in LDS.
//   A-frags (Wcat rows) and B-frags (gathered X rows) are loaded straight
//   from global into VGPRs: lane(lr,quad) loads 16B of row (.. + lr) at
//   k-chunk quad -- 4 quads of one row = one 64B line (coalesced gather).
//   W slice per k-step is 16KB, X slice 8KB: both L1-resident; W shared by
//   all blocks -> L2/L3. Double-buffered in registers two k-chunks deep.
// Phase 2: out = conv3 GEMM (A = WAp via registers, B = Z from LDS) + bias
//   + residual (+ fused next-layer xT write, o-major packed ushort4).
// Only TWO barriers per block (sRow init, Z publish). Waves run free.
// Z swizzle: chunk XOR (zr&7) (v3 layout, verified correct).
// ---------------------------------------------------------------------------
constexpr int ZSZ = 130 * 256;     // u16, 66,560 B

__global__ __launch_bounds__(512, 2)
void k_fused(const u16* __restrict__ xTsrc, const float* __restrict__ d,
             const u16* __restrict__ Wl, const float* __restrict__ bS,
             const u16* __restrict__ WAl, const float* __restrict__ bA,
             float dil, const float* __restrict__ xres, float* __restrict__ out,
             u16* __restrict__ xTn, int writeXT, const u16* __restrict__ zrow)
{
    __shared__ u16 zsm[ZSZ];
    __shared__ int sRow[3][130];

    const int tid = threadIdx.x;
    const int b = blockIdx.z;
    const int t0 = blockIdx.x * 128;

    if (tid < 130) {
        int tz = t0 - 1 + tid;
        if (tz < 0 || tz >= Tn) {
            sRow[0][tid] = -1; sRow[1][tid] = -1; sRow[2][tid] = -1;
        } else {
            float dv = d[(size_t)b * Tn + tz] * dil;
            int ip = (int)rintf((float)tz - dv);   // round-half-even == jnp.round
            int iF = (int)rintf((float)tz + dv);
            sRow[0][tid] = tz;
            sRow[1][tid] = (ip >= 0) ? ip : -1;
            sRow[2][tid] = (iF < Tn) ? iF : -1;
        }
    }
    __syncthreads();

    const int lane = tid & 63, wv = tid >> 6;
    const int mo  = (wv & 3) * 64;        // m (=o) offset, both phases
    const int wzr = (wv >> 2) * 64;       // n offset: zr (phase 1) / t (phase 2)
    const bool heavy = (wzr == 64);       // owns halo n-tile zr 128..143
    const int lr = lane & 15, quad = lane >> 4;

    const u16* xTb = xTsrc + (size_t)b * Tn * Cn;
    const char* xbc = (const char*)xTb;
    const int zoffq = (int)((const char*)zrow - xbc) + quad * 16;

    // per-lane gather byte-offsets (from xbc), one per (seg, ni) + halo
    int offB[3][4];
    #pragma unroll
    for (int ni = 0; ni < 4; ++ni) {
        int zr = wzr + ni * 16 + lr;
        #pragma unroll
        for (int s = 0; s < 3; ++s) {
            int r = sRow[s][zr];
            offB[s][ni] = (r >= 0) ? (r * (Cn * 2) + quad * 16) : zoffq;
        }
    }
    int offH[3] = { zoffq, zoffq, zoffq };
    if (heavy && lr < 2) {
        #pragma unroll
        for (int s = 0; s < 3; ++s) {
            int r = sRow[s][128 + lr];
            offH[s] = (r >= 0) ? (r * (Cn * 2) + quad * 16) : zoffq;
        }
    }

    // W row base pointers (A-frags): row = mo + mi*16 + lr, k-sub = quad
    const u16* wp1 = Wl  + (size_t)(mo + lr) * Kc + quad * 8;
    const u16* wp2 = WAl + (size_t)(mo + lr) * Kc + quad * 8;

    const f32x4 zv4 = {0.f, 0.f, 0.f, 0.f};
    f32x4 acc[4][5];
    #pragma unroll
    for (int mi = 0; mi < 4; ++mi)
        #pragma unroll
        for (int ni = 0; ni < 5; ++ni) acc[mi][ni] = zv4;

    // ---------------- phase 1: Z GEMM (register-direct operands) -----------
    {
        auto loadA = [&](int kg, bf8* a) {
            #pragma unroll
            for (int mi = 0; mi < 4; ++mi)
                a[mi] = *(const bf8*)(wp1 + (size_t)mi * 16 * Kc + kg * 32);
        };
        auto loadB = [&](int kg, bf8* bv) {
            int seg = kg >> 3, kb = (kg & 7) * 64;
            #pragma unroll
            for (int ni = 0; ni < 4; ++ni)
                bv[ni] = *(const bf8*)(xbc + offB[seg][ni] + kb);
            if (heavy)
                bv[4] = *(const bf8*)(xbc + offH[seg] + kb);
        };
        auto mm = [&](const bf8* a, const bf8* bv) {
            __builtin_amdgcn_s_setprio(1);
            #pragma unroll
            for (int mi = 0; mi < 4; ++mi)
                #pragma unroll
                for (int ni = 0; ni < 4; ++ni)
                    acc[mi][ni] = __builtin_amdgcn_mfma_f32_16x16x32_bf16(
                        a[mi], bv[ni], acc[mi][ni], 0, 0, 0);
            if (heavy) {
                #pragma unroll
                for (int mi = 0; mi < 4; ++mi)
                    acc[mi][4] = __builtin_amdgcn_mfma_f32_16x16x32_bf16(
                        a[mi], bv[4], acc[mi][4], 0, 0, 0);
            }
            __builtin_amdgcn_s_setprio(0);
        };

        bf8 aA[4], bA_[5] = {}, aB[4], bB_[5] = {};
        loadA(0, aA); loadB(0, bA_);
        #pragma unroll
        for (int kg = 0; kg < 24; kg += 2) {
            loadA(kg + 1, aB); loadB(kg + 1, bB_);
            mm(aA, bA_);
            if (kg + 2 < 24) { loadA(kg + 2, aA); loadB(kg + 2, bA_); }
            mm(aB, bB_);
        }
    }

    // ---------------- Z write (bf16, swizzled, zero invalid tz) ------------
    {
        float4 bSv[4];
        #pragma unroll
        for (int mi = 0; mi < 4; ++mi)
            bSv[mi] = *(const float4*)(bS + mo + mi * 16 + quad * 4);

        #pragma unroll
        for (int ni = 0; ni < 4; ++ni) {
            int zr = wzr + ni * 16 + lr;
            int tz = t0 - 1 + zr;
            bool vz = (tz >= 0) && (tz < Tn);
            #pragma unroll
            for (int mi = 0; mi < 4; ++mi) {
                int ob = mo + mi * 16 + quad * 4;
                ushort4 pk;
                #pragma unroll
                for (int r = 0; r < 4; ++r) {
                    float v = acc[mi][ni][r] + ((const float*)&bSv[mi])[r];
                    ((u16*)&pk)[r] = vz ? f2bf(lrelu(v)) : (u16)0;
                }
                int zi = zr * 256 + ((((ob >> 3) ^ (zr & 7)) << 3) | (ob & 7));
                *(ushort4*)(zsm + zi) = pk;
            }
        }
        if (heavy && lr < 2) {   // halo rows zr = 128,129
            int zr = 128 + lr;
            int tz = t0 - 1 + zr;
            bool vz = (tz >= 0) && (tz < Tn);
            #pragma unroll
            for (int mi = 0; mi < 4; ++mi) {
                int ob = mo + mi * 16 + quad * 4;
                ushort4 pk;
                #pragma unroll
                for (int r = 0; r < 4; ++r) {
                    float v = acc[mi][4][r] + ((const float*)&bSv[mi])[r];
                    ((u16*)&pk)[r] = vz ? f2bf(lrelu(v)) : (u16)0;
                }
                int zi = zr * 256 + ((((ob >> 3) ^ (zr & 7)) << 3) | (ob & 7));
                *(ushort4*)(zsm + zi) = pk;
            }
        }
    }
    __syncthreads();   // Z visible to all waves

    // ---------------- phase 2: conv3 GEMM (A = WAp regs, B = Z LDS) --------
    #pragma unroll
    for (int mi = 0; mi < 4; ++mi)
        #pragma unroll
        for (int ni = 0; ni < 4; ++ni) acc[mi][ni] = zv4;

    {
        auto loadA = [&](int kg, bf8* a) {
            #pragma unroll
            for (int mi = 0; mi < 4; ++mi)
                a[mi] = *(const bf8*)(wp2 + (size_t)mi * 16 * Kc + kg * 32);
        };
        auto loadB = [&](int kg, bf8* bv) {
            int tap = kg >> 3, cI = (kg & 7) * 4 + quad;
            #pragma unroll
            for (int ni = 0; ni < 4; ++ni) {
                int zr = wzr + ni * 16 + lr + tap;   // 0..129
                bv[ni] = *(const bf8*)(zsm + zr * 256 + ((cI ^ (zr & 7)) << 3));
            }
        };
        auto mm = [&](const bf8* a, const bf8* bv) {
            __builtin_amdgcn_s_setprio(1);
            #pragma unroll
            for (int mi = 0; mi < 4; ++mi)
                #pragma unroll
                for (int ni = 0; ni < 4; ++ni)
                    acc[mi][ni] = __builtin_amdgcn_mfma_f32_16x16x32_bf16(
                        a[mi], bv[ni], acc[mi][ni], 0, 0, 0);
            __builtin_amdgcn_s_setprio(0);
        };

        bf8 aA[4], bA_[4], aB[4], bB_[4];
        loadA(0, aA); loadB(0, bA_);
        #pragma unroll
        for (int kg = 0; kg < 24; kg += 2) {
            loadA(kg + 1, aB); loadB(kg + 1, bB_);
            mm(aA, bA_);
            if (kg + 2 < 24) { loadA(kg + 2, aA); loadB(kg + 2, bA_); }
            mm(aB, bB_);
        }
    }

    // ---------------- epilogue: bias + residual (+ fused next-layer xT) ----
    {
        float4 bAv[4];
        #pragma unroll
        for (int mi = 0; mi < 4; ++mi)
            bAv[mi] = *(const float4*)(bA + mo + mi * 16 + quad * 4);

        #pragma unroll
        for (int mi = 0; mi < 4; ++mi) {
            int ob = mo + mi * 16 + quad * 4;
            #pragma unroll
            for (int ni = 0; ni < 4; ++ni) {
                int t = t0 + wzr + ni * 16 + lr;
                ushort4 px;
                #pragma unroll
                for (int r = 0; r < 4; ++r) {
                    size_t idx = ((size_t)b * Cn + ob + r) * Tn + t;
                    float v = acc[mi][ni][r] + ((const float*)&bAv[mi])[r] + xres[idx];
                    out[idx] = v;
                    ((u16*)&px)[r] = f2bf(lrelu(v));
                }
                if (writeXT)
                    *(ushort4*)(xTn + ((size_t)b * Tn + t) * Cn + ob) = px;
            }
        }
    }
}

extern "C" void kernel_launch(void* const* d_in, const int* in_sizes, int n_in,
                              void* d_out, int out_size, void* d_ws, size_t ws_size,
                              hipStream_t stream)
{
    const float* x  = (const float*)d_in[0];
    const float* d  = (const float*)d_in[1];
    const float* WC = (const float*)d_in[2];
    const float* bC = (const float*)d_in[3];
    const float* WP = (const float*)d_in[4];
    const float* bP = (const float*)d_in[5];
    const float* WF = (const float*)d_in[6];
    const float* bF = (const float*)d_in[7];
    const float* WA = (const float*)d_in[8];
    const float* bA = (const float*)d_in[9];
    float* out = (float*)d_out;

    char* ws = (char*)d_ws;
    u16*   xTa  = (u16*)(ws);                                   // 32 MiB
    u16*   xTb  = (u16*)(ws + (size_t)Bn * Tn * Cn * 2);        // 32 MiB (ping-pong)
    u16*   Wcat = (u16*)(ws + (size_t)2 * Bn * Tn * Cn * 2);    // 1.125 MiB
    u16*   WAp  = Wcat + (size_t)NL * Cn * Kc;                  // 1.125 MiB
    float* bSum = (float*)(WAp + (size_t)NL * Cn * Kc);         // 3 KiB
    u16*   zrow = (u16*)(bSum + NL * Cn);                       // 512 B zero row

    k_wprep<<<dim3(1024), dim3(256), 0, stream>>>(WC, WP, WF, WA, bC, bP, bF,
                                                  Wcat, WAp, bSum, zrow);

    dim3 gP(Tn / 64, Cn / 64, Bn);      // prep: 128 x 4 x 8
    k_prep<<<gP, dim3(256), 0, stream>>>(x, xTa);   // layer-0 input only

    const float dils[NL] = {1.f, 2.f, 4.f};
    const float* xcur = x;
    u16* xsrc = xTa;
    u16* xdst = xTb;
    for (int i = 0; i < NL; ++i) {
        k_fused<<<dim3(Tn / 128, 1, Bn), dim3(512), 0, stream>>>(
            xsrc, d,
            Wcat + (size_t)i * Cn * Kc, bSum + (size_t)i * Cn,
            WAp  + (size_t)i * Cn * Kc, bA + (size_t)i * Cn,
            dils[i], xcur, out, xdst, (i < NL - 1) ? 1 : 0, zrow);
        xcur = out;   // residual read-then-write same element: in-place safe
        u16* tmp = xsrc; xsrc = xdst; xdst = tmp;
    }
}

// Round 5
// 373.559 us; speedup vs baseline: 1.6367x; 1.6367x over previous
//
#include <hip/hip_runtime.h>
#include <hip/hip_bf16.h>
#include <cstddef>
#include <cstdint>

constexpr int Bn = 8, Cn = 256, Tn = 8192;
constexpr int NL = 3;          // layers / dilations (1,2,4)
constexpr int Kc = 768;        // K for both fused GEMMs (3*256)
constexpr float SLOPE = 0.1f;

typedef unsigned short u16;
using bf8   = __attribute__((ext_vector_type(8))) short;  // 8 bf16 = 4 VGPRs
using f32x4 = __attribute__((ext_vector_type(4))) float;

__device__ __forceinline__ float lrelu(float v) { return v > 0.f ? v : SLOPE * v; }
__device__ __forceinline__ u16 f2bf(float f) {
    __hip_bfloat16 h = __float2bfloat16(f);
    return *reinterpret_cast<u16*>(&h);
}

// async global->LDS, 16B per lane. LDS dest is wave-uniform base + lane*16:
// must be issued with ALL lanes active; invalid rows redirect the GLOBAL
// pointer to a zero row (per-lane global addresses are fine).
__device__ __forceinline__ void g2l16(const u16* g, u16* l) {
    __builtin_amdgcn_global_load_lds(
        (const __attribute__((address_space(1))) char*)g,
        (__attribute__((address_space(3))) char*)l, 16, 0, 0);
}

// raw barrier for the pipeline: each wave has already drained its own DMA
// (vmcnt) and LDS reads (lgkmcnt) via the preceding asm; sched_barrier(0)
// stops the compiler moving the next phase's memory ops above the barrier.
__device__ __forceinline__ void pipe_barrier() {
    __builtin_amdgcn_s_barrier();
    __builtin_amdgcn_sched_barrier(0);
}

// ---------------------------------------------------------------------------
// Weight prep (once): bf16 Wcat[l][o][s*256+c] from WC/WP/WF,
// bf16 WAp[l][o][tap*256+c] from WA[l][o][c][tap], bSum = bC+bP+bF,
// zero dummy row (ws re-poisoned each launch).
// ---------------------------------------------------------------------------
__global__ __launch_bounds__(256)
void k_wprep(const float* __restrict__ WC, const float* __restrict__ WP,
             const float* __restrict__ WF, const float* __restrict__ WA,
             const float* __restrict__ bC, const float* __restrict__ bP,
             const float* __restrict__ bF,
             u16* __restrict__ Wcat, u16* __restrict__ WAp, float* __restrict__ bSum,
             u16* __restrict__ zrow)
{
    if (blockIdx.x == 0) zrow[threadIdx.x] = 0;
    const int n1 = NL * Cn * Kc;
    for (int i = blockIdx.x * blockDim.x + threadIdx.x; i < n1;
         i += gridDim.x * blockDim.x) {
        int c = i % Cn;
        int s = (i / Cn) % 3;
        int o = (i / (3 * Cn)) % Cn;
        int l = i / (3 * Cn * Cn);
        size_t src = ((size_t)l * Cn + o) * Cn + c;
        float wc = (s == 0) ? WC[src] : (s == 1) ? WP[src] : WF[src];
        Wcat[i] = f2bf(wc);
        WAp[i] = f2bf(WA[src * 3 + s]);
    }
    for (int i = blockIdx.x * blockDim.x + threadIdx.x; i < NL * Cn;
         i += gridDim.x * blockDim.x)
        bSum[i] = bC[i] + bP[i] + bF[i];
}

// ---------------------------------------------------------------------------
// Layer-0 prep: xT[b][t][c] = bf16(lrelu(x[b][c][t]))  (transpose via LDS)
// ---------------------------------------------------------------------------
__global__ __launch_bounds__(256)
void k_prep(const float* __restrict__ x, u16* __restrict__ xT)
{
    __shared__ float s[64][65];
    const int b = blockIdx.z, c0 = blockIdx.y * 64, t0 = blockIdx.x * 64;
    const int tid = threadIdx.x;
    const float* xb = x + ((size_t)b * Cn + c0) * Tn + t0;

    int tt = tid & 63, c4 = tid >> 6;
    for (int cc = c4; cc < 64; cc += 4)
        s[cc][tt] = xb[(size_t)cc * Tn + tt];
    __syncthreads();

    int ccS = tid & 63, t4 = tid >> 6;
    u16* xTb = xT + ((size_t)b * Tn + t0) * Cn + c0;
    for (int t2 = t4; t2 < 64; t2 += 4)
        xTb[(size_t)t2 * Cn + ccS] = f2bf(lrelu(s[ccS][t2]));
}

// ---------------------------------------------------------------------------
// GEMM1: zT[b][t][o] = bf16(lrelu( sum_k Xcat[t][k]*Wcat[o][k] + bSum[o] ))
//   A = X (m=t), B = W (n=o). 128x128 tile, 4 waves of 64x64.
//   XCD pair-swizzle: fid -> xcd=fid&7 owns 8 consecutive t-tiles x both
//   o-halves, so the o-pair shares X-gather rows in its private L2.
//   K-loop: ring-4 LDS slots, 12 phases of 2 K-chunks each (half the
//   barriers of R1). DMA for the next 2 slots issued right after the
//   barrier (slots read last phase -- safe); chunk k+1's ds_read latency
//   hidden under chunk k's MFMA via split lgkmcnt(8)/lgkmcnt(0).
//   Bank-conflict fix (verified R1): source-side chunk XOR + read-side XOR.
// ---------------------------------------------------------------------------
__global__ __launch_bounds__(256, 2)
void k_gemm1(const u16* __restrict__ xT, const float* __restrict__ d,
             const u16* __restrict__ Wl, const float* __restrict__ bS,
             float dil, u16* __restrict__ zT, const u16* __restrict__ zrow)
{
    __shared__ u16 smem[8 * 4096];   // X slots 0..3, then W slots 0..3 (8KB each)
    __shared__ int sRow[3][128];

    const int tid = threadIdx.x;
    const int b = blockIdx.z;
    const int fid = blockIdx.x;               // 0..127
    const int j = fid >> 3;
    const int o0 = (j & 1) * 128;
    const int t0 = ((fid & 7) * 8 + (j >> 1)) * 128;

    if (tid < 128) {
        int t = t0 + tid;
        float dv = d[(size_t)b * Tn + t] * dil;
        int ip = (int)rintf((float)t - dv);   // round-half-even == jnp.round
        int iF = (int)rintf((float)t + dv);
        sRow[0][tid] = t;
        sRow[1][tid] = (ip >= 0) ? ip : -1;
        sRow[2][tid] = (iF < Tn) ? iF : -1;
    }
    __syncthreads();

    const int srow = tid >> 2;                 // 0..63 (rows srow, srow+64)
    const int schunkL = (tid & 3) * 8;                       // linear LDS slot
    const int schunkG = ((tid & 3) ^ ((tid >> 3) & 3)) * 8;  // swizzled source
    const u16* xTb = xT + (size_t)b * Tn * Cn;

    const u16 *pr0[3], *pr1[3];
    #pragma unroll
    for (int s = 0; s < 3; ++s) {
        int r0 = sRow[s][srow], r1 = sRow[s][srow + 64];
        pr0[s] = (r0 >= 0) ? (xTb + (size_t)r0 * Cn + schunkG) : (zrow + schunkG);
        pr1[s] = (r1 >= 0) ? (xTb + (size_t)r1 * Cn + schunkG) : (zrow + schunkG);
    }
    const u16* wbase = Wl + (size_t)(o0 + srow) * Kc + schunkG;

    const int lane = tid & 63, wv = tid >> 6;
    const int wm = (wv & 1) * 64;   // t-half
    const int wn = (wv >> 1) * 64;  // o-half
    const int lr = lane & 15, quad = lane >> 4;
    const int rchunk = (quad ^ ((lr >> 1) & 3)) * 8;   // read-side un-swizzle

    const int ldsW = srow * 32 + schunkL;          // this thread's DMA slot
    const int ldsW2 = (srow + 64) * 32 + schunkL;

    auto dma = [&](int kg, int bsel) {
        int seg = kg >> 3, kk = (kg & 7) * 32;
        u16* bx = smem + bsel * 4096;
        u16* bw = smem + 16384 + bsel * 4096;
        g2l16(wbase + seg * 256 + kk,                   bw + ldsW);
        g2l16(wbase + (size_t)64 * Kc + seg * 256 + kk, bw + ldsW2);
        g2l16(pr0[seg] + kk, bx + ldsW);
        g2l16(pr1[seg] + kk, bx + ldsW2);
    };

    f32x4 acc[4][4] = {};
    dma(0, 0); dma(1, 1);

    #pragma unroll
    for (int P = 0; P < 12; ++P) {
        const int k0 = 2 * P, k1 = 2 * P + 1;
        asm volatile("s_waitcnt vmcnt(0) lgkmcnt(0)" ::: "memory");
        pipe_barrier();
        if (P < 11) { dma(k0 + 2, (k0 + 2) & 3); dma(k1 + 2, (k1 + 2) & 3); }
        __builtin_amdgcn_sched_barrier(0);

        const u16* bX0 = smem + (k0 & 3) * 4096;
        const u16* bW0 = smem + 16384 + (k0 & 3) * 4096;
        const u16* bX1 = smem + (k1 & 3) * 4096;
        const u16* bW1 = smem + 16384 + (k1 & 3) * 4096;

        bf8 a0[4], g0[4], a1[4], g1[4];
        #pragma unroll
        for (int mi = 0; mi < 4; ++mi)
            a0[mi] = *(const bf8*)(bX0 + (wm + mi * 16 + lr) * 32 + rchunk);
        #pragma unroll
        for (int ni = 0; ni < 4; ++ni)
            g0[ni] = *(const bf8*)(bW0 + (wn + ni * 16 + lr) * 32 + rchunk);
        __builtin_amdgcn_sched_barrier(0);
        #pragma unroll
        for (int mi = 0; mi < 4; ++mi)
            a1[mi] = *(const bf8*)(bX1 + (wm + mi * 16 + lr) * 32 + rchunk);
        #pragma unroll
        for (int ni = 0; ni < 4; ++ni)
            g1[ni] = *(const bf8*)(bW1 + (wn + ni * 16 + lr) * 32 + rchunk);

        asm volatile("s_waitcnt lgkmcnt(8)" ::: "memory");
        __builtin_amdgcn_sched_barrier(0);
        __builtin_amdgcn_s_setprio(1);
        #pragma unroll
        for (int mi = 0; mi < 4; ++mi)
            #pragma unroll
            for (int ni = 0; ni < 4; ++ni)
                acc[mi][ni] = __builtin_amdgcn_mfma_f32_16x16x32_bf16(
                    a0[mi], g0[ni], acc[mi][ni], 0, 0, 0);
        __builtin_amdgcn_s_setprio(0);

        asm volatile("s_waitcnt lgkmcnt(0)" ::: "memory");
        __builtin_amdgcn_sched_barrier(0);
        __builtin_amdgcn_s_setprio(1);
        #pragma unroll
        for (int mi = 0; mi < 4; ++mi)
            #pragma unroll
            for (int ni = 0; ni < 4; ++ni)
                acc[mi][ni] = __builtin_amdgcn_mfma_f32_16x16x32_bf16(
                    a1[mi], g1[ni], acc[mi][ni], 0, 0, 0);
        __builtin_amdgcn_s_setprio(0);
    }

    // epilogue: D row = m = t (quad*4+r), col = n = o (lr)
    float bias[4];
    #pragma unroll
    for (int ni = 0; ni < 4; ++ni) bias[ni] = bS[o0 + wn + ni * 16 + lr];
    u16* zTb = zT + (size_t)b * Tn * Cn;
    #pragma unroll
    for (int mi = 0; mi < 4; ++mi)
        #pragma unroll
        for (int r = 0; r < 4; ++r) {
            int t = t0 + wm + mi * 16 + quad * 4 + r;
            u16* row = zTb + (size_t)t * Cn + o0 + wn;
            #pragma unroll
            for (int ni = 0; ni < 4; ++ni)
                row[ni * 16 + lr] = f2bf(lrelu(acc[mi][ni][r] + bias[ni]));
        }
}

// ---------------------------------------------------------------------------
// GEMM2 (conv3 + residual + fused next-layer prep):
//   out[b][o][t] = sum_{tap,c} WAp[o][tap*256+c]*zT[t+tap-1][c] + bA[o] + xres
//   if writeXT: xTn[b][t][o] = bf16(lrelu(out))  (per-wave LDS transpose)
//   A = W (m=o), B = Z (n=t). Same 2-kg-phase pipeline + XCD pair swizzle.
// ---------------------------------------------------------------------------
__global__ __launch_bounds__(256, 2)
void k_gemm2(const u16* __restrict__ zT, const u16* __restrict__ WAl,
             const float* __restrict__ bA, const float* __restrict__ xres,
             float* __restrict__ out, u16* __restrict__ xTn, int writeXT,
             const u16* __restrict__ zrow)
{
    __shared__ u16 smem[8 * 4096];   // Z slots 0..3, W slots 0..3; epilogue reuses

    const int tid = threadIdx.x;
    const int b = blockIdx.z;
    const int fid = blockIdx.x;               // 0..127
    const int j = fid >> 3;
    const int o0 = (j & 1) * 128;
    const int t0 = ((fid & 7) * 8 + (j >> 1)) * 128;

    const int srow = tid >> 2;
    const int schunkL = (tid & 3) * 8;
    const int schunkG = ((tid & 3) ^ ((tid >> 3) & 3)) * 8;
    const int lane = tid & 63, wv = tid >> 6;
    const int wo = (wv & 1) * 64;   // o-half (m)
    const int wt = (wv >> 1) * 64;  // t-half (n)
    const int lr = lane & 15, quad = lane >> 4;
    const int rchunk = (quad ^ ((lr >> 1) & 3)) * 8;

    const u16* zTb = zT + (size_t)b * Tn * Cn;
    const u16 *zr0[3], *zr1[3];
    #pragma unroll
    for (int tap = 0; tap < 3; ++tap) {
        int r0 = t0 + srow + tap - 1;
        int r1 = r0 + 64;
        zr0[tap] = (r0 >= 0 && r0 < Tn) ? (zTb + (size_t)r0 * Cn + schunkG)
                                        : (zrow + schunkG);
        zr1[tap] = (r1 >= 0 && r1 < Tn) ? (zTb + (size_t)r1 * Cn + schunkG)
                                        : (zrow + schunkG);
    }
    const u16* wbase = WAl + (size_t)(o0 + srow) * Kc + schunkG;

    const int ldsW = srow * 32 + schunkL;
    const int ldsW2 = (srow + 64) * 32 + schunkL;

    auto dma = [&](int kg, int bsel) {
        int tap = kg >> 3, kk = (kg & 7) * 32;
        u16* bz = smem + bsel * 4096;
        u16* bw = smem + 16384 + bsel * 4096;
        g2l16(wbase + tap * 256 + kk,                   bw + ldsW);
        g2l16(wbase + (size_t)64 * Kc + tap * 256 + kk, bw + ldsW2);
        g2l16(zr0[tap] + kk, bz + ldsW);
        g2l16(zr1[tap] + kk, bz + ldsW2);
    };

    f32x4 acc[4][4] = {};
    dma(0, 0); dma(1, 1);

    #pragma unroll
    for (int P = 0; P < 12; ++P) {
        const int k0 = 2 * P, k1 = 2 * P + 1;
        asm volatile("s_waitcnt vmcnt(0) lgkmcnt(0)" ::: "memory");
        pipe_barrier();
        if (P < 11) { dma(k0 + 2, (k0 + 2) & 3); dma(k1 + 2, (k1 + 2) & 3); }
        __builtin_amdgcn_sched_barrier(0);

        const u16* bZ0 = smem + (k0 & 3) * 4096;
        const u16* bW0 = smem + 16384 + (k0 & 3) * 4096;
        const u16* bZ1 = smem + (k1 & 3) * 4096;
        const u16* bW1 = smem + 16384 + (k1 & 3) * 4096;

        bf8 a0[4], g0[4], a1[4], g1[4];
        #pragma unroll
        for (int mi = 0; mi < 4; ++mi)
            a0[mi] = *(const bf8*)(bW0 + (wo + mi * 16 + lr) * 32 + rchunk);
        #pragma unroll
        for (int ni = 0; ni < 4; ++ni)
            g0[ni] = *(const bf8*)(bZ0 + (wt + ni * 16 + lr) * 32 + rchunk);
        __builtin_amdgcn_sched_barrier(0);
        #pragma unroll
        for (int mi = 0; mi < 4; ++mi)
            a1[mi] = *(const bf8*)(bW1 + (wo + mi * 16 + lr) * 32 + rchunk);
        #pragma unroll
        for (int ni = 0; ni < 4; ++ni)
            g1[ni] = *(const bf8*)(bZ1 + (wt + ni * 16 + lr) * 32 + rchunk);

        asm volatile("s_waitcnt lgkmcnt(8)" ::: "memory");
        __builtin_amdgcn_sched_barrier(0);
        __builtin_amdgcn_s_setprio(1);
        #pragma unroll
        for (int mi = 0; mi < 4; ++mi)
            #pragma unroll
            for (int ni = 0; ni < 4; ++ni)
                acc[mi][ni] = __builtin_amdgcn_mfma_f32_16x16x32_bf16(
                    a0[mi], g0[ni], acc[mi][ni], 0, 0, 0);
        __builtin_amdgcn_s_setprio(0);

        asm volatile("s_waitcnt lgkmcnt(0)" ::: "memory");
        __builtin_amdgcn_sched_barrier(0);
        __builtin_amdgcn_s_setprio(1);
        #pragma unroll
        for (int mi = 0; mi < 4; ++mi)
            #pragma unroll
            for (int ni = 0; ni < 4; ++ni)
                acc[mi][ni] = __builtin_amdgcn_mfma_f32_16x16x32_bf16(
                    a1[mi], g1[ni], acc[mi][ni], 0, 0, 0);
        __builtin_amdgcn_s_setprio(0);
    }

    float biasv[4][4];
    #pragma unroll
    for (int mi = 0; mi < 4; ++mi) {
        float4 bb = *(const float4*)(bA + o0 + wo + mi * 16 + quad * 4);
        biasv[mi][0] = bb.x; biasv[mi][1] = bb.y; biasv[mi][2] = bb.z; biasv[mi][3] = bb.w;
    }

    if (writeXT) {
        // per-wave 16t x 64o strips, padded rows (72 u16 = 144B)
        u16* strip = smem + wv * 1152;
        u16* xTb2 = xTn + (size_t)b * Tn * Cn;
        #pragma unroll
        for (int ni = 0; ni < 4; ++ni) {
            __syncthreads();   // staging/strip LDS free of readers
            #pragma unroll
            for (int mi = 0; mi < 4; ++mi) {
                ushort4 pk;
                #pragma unroll
                for (int r = 0; r < 4; ++r) {
                    int o = o0 + wo + mi * 16 + quad * 4 + r;
                    size_t idx = ((size_t)b * Cn + o) * Tn + t0 + wt + ni * 16 + lr;
                    float v = acc[mi][ni][r] + biasv[mi][r] + xres[idx];
                    out[idx] = v;
                    ((u16*)&pk)[r] = f2bf(lrelu(v));
                }
                *(ushort4*)(strip + lr * 72 + mi * 16 + quad * 4) = pk;
            }
            __syncthreads();   // strip writes visible
            #pragma unroll
            for (int it = 0; it < 2; ++it) {
                int tt = (lane >> 3) + it * 8;
                uint4 vv = *(const uint4*)(strip + tt * 72 + (lane & 7) * 8);
                *(uint4*)(xTb2 + (size_t)(t0 + wt + ni * 16 + tt) * Cn
                          + o0 + wo + (lane & 7) * 8) = vv;
            }
        }
    } else {
        #pragma unroll
        for (int mi = 0; mi < 4; ++mi)
            #pragma unroll
            for (int r = 0; r < 4; ++r) {
                int o = o0 + wo + mi * 16 + quad * 4 + r;
                size_t base = ((size_t)b * Cn + o) * Tn + t0 + wt;
                #pragma unroll
                for (int ni = 0; ni < 4; ++ni) {
                    size_t idx = base + ni * 16 + lr;
                    out[idx] = acc[mi][ni][r] + biasv[mi][r] + xres[idx];
                }
            }
    }
}

extern "C" void kernel_launch(void* const* d_in, const int* in_sizes, int n_in,
                              void* d_out, int out_size, void* d_ws, size_t ws_size,
                              hipStream_t stream)
{
    const float* x  = (const float*)d_in[0];
    const float* d  = (const float*)d_in[1];
    const float* WC = (const float*)d_in[2];
    const float* bC = (const float*)d_in[3];
    const float* WP = (const float*)d_in[4];
    const float* bP = (const float*)d_in[5];
    const float* WF = (const float*)d_in[6];
    const float* bF = (const float*)d_in[7];
    const float* WA = (const float*)d_in[8];
    const float* bA = (const float*)d_in[9];
    float* out = (float*)d_out;

    char* ws = (char*)d_ws;
    u16*   xT   = (u16*)(ws);                                   // 32 MiB
    u16*   zT   = (u16*)(ws + (size_t)Bn * Tn * Cn * 2);        // 32 MiB
    u16*   Wcat = (u16*)(ws + (size_t)2 * Bn * Tn * Cn * 2);    // 1.125 MiB
    u16*   WAp  = Wcat + (size_t)NL * Cn * Kc;                  // 1.125 MiB
    float* bSum = (float*)(WAp + (size_t)NL * Cn * Kc);         // 3 KiB
    u16*   zrow = (u16*)(bSum + NL * Cn);                       // 512 B zero row

    k_wprep<<<dim3(1024), dim3(256), 0, stream>>>(WC, WP, WF, WA, bC, bP, bF,
                                                  Wcat, WAp, bSum, zrow);

    dim3 gP(Tn / 64, Cn / 64, Bn);      // prep: 128 x 4 x 8
    dim3 gG(128, 1, Bn);                // gemms: flat 128 tiles x 8 batches
    dim3 blk(256);

    k_prep<<<gP, blk, 0, stream>>>(x, xT);   // layer-0 input only

    const float dils[NL] = {1.f, 2.f, 4.f};
    const float* xcur = x;
    for (int i = 0; i < NL; ++i) {
        k_gemm1<<<gG, blk, 0, stream>>>(xT, d,
                                        Wcat + (size_t)i * Cn * Kc,
                                        bSum + (size_t)i * Cn,
                                        dils[i], zT, zrow);
        k_gemm2<<<gG, blk, 0, stream>>>(zT,
                                        WAp + (size_t)i * Cn * Kc,
                                        bA + (size_t)i * Cn,
                                        xcur, out, xT, (i < NL - 1) ? 1 : 0,
                                        zrow);
        xcur = out;   // residual read-then-write same element: in-place safe
    }
}